// Round 11
// baseline (6556.490 us; speedup 1.0000x reference)
//
#include <hip/hip_runtime.h>
#include <hip/hip_bf16.h>

#define H_ 1024
#define C_ 1536
#define B_ 256
#define T_ 128
#define IN_ 512
#define BH_ (B_*H_)
#define NGEMM 704
#define NBLK  960

typedef __hip_bfloat16 bf16;
typedef __attribute__((ext_vector_type(8))) short short8;
typedef __attribute__((ext_vector_type(4))) float f32x4;
typedef unsigned int u32;
typedef unsigned long long u64;

struct WPtrs { const float* W[10]; const float* wA; };
struct BPtrs { const float* b[10]; const float* bA[4]; };

__device__ __forceinline__ float sigmf(float x){ return 1.0f/(1.0f + __expf(-x)); }
__device__ __forceinline__ float tanhfast(float x){ return 1.0f - 2.0f/(__expf(2.0f*x) + 1.0f); }

__device__ __forceinline__ ushort bf16bits(float f){
    bf16 b = __float2bfloat16(f);
    return *reinterpret_cast<ushort*>(&b);
}

// coherent (cross-XCD) helpers — proven r6-r9
__device__ __forceinline__ void astoref(float* p, float v){
    __hip_atomic_store(p, v, __ATOMIC_RELAXED, __HIP_MEMORY_SCOPE_AGENT);
}
__device__ __forceinline__ u64 aload64(const u64* p){
    return __hip_atomic_load(p, __ATOMIC_RELAXED, __HIP_MEMORY_SCOPE_AGENT);
}

// async global->LDS, 16B per lane (plain cached path)
__device__ __forceinline__ void gload16(const void* g, void* l){
    __builtin_amdgcn_global_load_lds((const __attribute__((address_space(1))) u32*)g,
                                     (__attribute__((address_space(3))) u32*)l, 16, 0, 0);
}

// ---- weight transpose+convert: src fp32 [K][H] -> dst bf16 [H][K]
__global__ void transpose_w(WPtrs wp, ushort* __restrict__ Wt, ushort* __restrict__ wAt)
{
    int g = blockIdx.z;
    int K = (g==10) ? H_ : C_;
    int k0 = blockIdx.x*32, n0 = blockIdx.y*32;
    if (k0 >= K) return;
    const float* src = (g==10) ? wp.wA : wp.W[g];
    __shared__ float tile[32][33];
    int tx = threadIdx.x, ty = threadIdx.y;
    #pragma unroll
    for (int i=0;i<32;i+=8)
        tile[ty+i][tx] = src[(size_t)(k0+ty+i)*H_ + n0 + tx];
    __syncthreads();
    ushort* dst = (g==10) ? wAt : (Wt + (size_t)g*H_*C_);
    #pragma unroll
    for (int i=0;i<32;i+=8)
        dst[(size_t)(n0+ty+i)*K + k0 + tx] = bf16bits(tile[tx][ty+i]);
}

// ---- fused per-step kernel: one dispatch per step.
// bids 0..703  : gemm (r10 internals; device-scope P stores; counter bump)
// bids 704..959: update row b=bid-704 (spin; coherent P reads; plain h/c/out stores)
__global__ __launch_bounds__(128, 2) void fused_step(
    const ushort* __restrict__ Wt, const ushort* __restrict__ wAt,
    const float* __restrict__ xY, const float* __restrict__ xI,
    const float* __restrict__ xPf, const float* __restrict__ xNf,
    ushort* __restrict__ hb, ushort* __restrict__ cbuf, float* __restrict__ c,
    float* __restrict__ P, BPtrs bp, float* __restrict__ out,
    u32* __restrict__ cnts, int t)
{
    int bid = blockIdx.x;
    int tid = threadIdx.x;
    int wid = tid>>6, lane = tid&63;

    __shared__ ushort As[2][64*64];
    __shared__ ushort Bs[2][128*64];

    if (bid < NGEMM){
        // ================= gemm role =================
        int xcd = bid & 7, lid = bid >> 3;
        int ntile = xcd*11 + (lid >> 3);
        int rem = lid & 7;
        int mtile = rem >> 1;
        int split = rem & 1;
        int g = ntile >> 3;
        int n0g = (ntile & 7)*128;
        int m0 = mtile*64;
        bool isA = (g==10);
        const ushort* Bbase = isA ? wAt : (Wt + (size_t)g*H_*C_);
        size_t Bstride = isA ? 1024 : 1536;
        int kStart = isA ? split*512 : split*768;
        int nIter  = isA ? 8 : 12;
        const float* xf = (g==3)?xI:(g==4)?xPf:(g==5)?xNf:xY;
        const ushort* Ah = isA ? cbuf : hb;

        float xr0[8], xr1[8], xr2[8], xr3[8];

        auto stageB = [&](int buf, int k0){
            ushort* lb = Bs[buf];
            #pragma unroll
            for (int it=0; it<8; ++it){
                int cid = it*128 + tid;
                int row = cid>>3, kc = cid&7;
                int kcs = kc ^ (row&7);
                gload16(Bbase + (size_t)(n0g+row)*Bstride + k0 + kcs*8,
                        lb + (size_t)(it*128 + wid*64)*8);
            }
        };
        auto stageA_h = [&](int buf, int k0){
            ushort* la = As[buf];
            #pragma unroll
            for (int it=0; it<4; ++it){
                int cid = it*128 + tid;
                int row = cid>>3, kc = cid&7;
                int kcs = kc ^ (row&7);
                gload16(Ah + (size_t)(m0+row)*H_ + k0 + kcs*8,
                        la + (size_t)(it*128 + wid*64)*8);
            }
        };
        auto stageX_issue = [&](int k0){
            #pragma unroll
            for (int it=0; it<4; ++it){
                int cid = it*128 + tid;
                int row = cid>>3, kc = cid&7;
                const float4* s4 = (const float4*)(xf + ((size_t)(m0+row)*T_ + t)*IN_ + (k0 + kc*8 - 1024));
                float4 a = s4[0], b = s4[1];
                float* xr = (it==0)?xr0:(it==1)?xr1:(it==2)?xr2:xr3;
                xr[0]=a.x; xr[1]=a.y; xr[2]=a.z; xr[3]=a.w;
                xr[4]=b.x; xr[5]=b.y; xr[6]=b.z; xr[7]=b.w;
            }
        };
        auto stageX_finish = [&](int buf){
            ushort* la = As[buf];
            #pragma unroll
            for (int it=0; it<4; ++it){
                int cid = it*128 + tid;
                int row = cid>>3, kc = cid&7;
                int kcs = kc ^ (row&7);
                const float* xr = (it==0)?xr0:(it==1)?xr1:(it==2)?xr2:xr3;
                ushort t8[8];
                #pragma unroll
                for (int q=0;q<8;++q) t8[q] = bf16bits(xr[q]);
                *(ulong2*)(la + (size_t)row*64 + kcs*8) = *(ulong2*)t8;
            }
        };

        f32x4 acc[4][4] = {};
        stageA_h(0, kStart);
        stageB(0, kStart);
        __syncthreads();

        int cur = 0;
        for (int i=0; i<nIter; ++i){
            int k0n = kStart + ((i+1)<<6);
            bool more = (i+1 < nIter);
            bool nx_x = false;
            if (more){
                nx_x = (!isA) && (k0n >= 1024);
                if (nx_x) stageX_issue(k0n);
                else      stageA_h(cur^1, k0n);
                stageB(cur^1, k0n);
            }
            ushort* la = As[cur];
            ushort* lb = Bs[cur];
            #pragma unroll
            for (int kk=0; kk<2; ++kk){
                short8 af[4], bfr[4];
                #pragma unroll
                for (int mr=0;mr<4;++mr){
                    int r = mr*16 + (lane&15);
                    int j = (kk*4 + (lane>>4)) ^ (r&7);
                    af[mr] = *(const short8*)(la + r*64 + j*8);
                }
                #pragma unroll
                for (int nr=0;nr<4;++nr){
                    int r = wid*64 + nr*16 + (lane&15);
                    int j = (kk*4 + (lane>>4)) ^ (r&7);
                    bfr[nr] = *(const short8*)(lb + r*64 + j*8);
                }
                #pragma unroll
                for (int mr=0;mr<4;++mr)
                    #pragma unroll
                    for (int nr=0;nr<4;++nr)
                        acc[mr][nr] = __builtin_amdgcn_mfma_f32_16x16x32_bf16(af[mr], bfr[nr], acc[mr][nr], 0,0,0);
            }
            if (more && nx_x) stageX_finish(cur^1);
            __syncthreads();
            cur ^= 1;
        }

        float* Pg = P + ((size_t)split*11 + g)*BH_;
        #pragma unroll
        for (int mr=0;mr<4;++mr){
            #pragma unroll
            for (int nr=0;nr<4;++nr){
                int col = n0g + wid*64 + nr*16 + (lane&15);
                #pragma unroll
                for (int r=0;r<4;++r){
                    int rowg = m0 + mr*16 + (lane>>4)*4 + r;
                    astoref(&Pg[(size_t)rowg*H_ + col], acc[mr][nr][r]);
                }
            }
        }
        asm volatile("s_waitcnt vmcnt(0)" ::: "memory");
        __syncthreads();
        if (tid == 0)
            __hip_atomic_fetch_add(&cnts[((bid & 15) << 6) + (t & 1)*16], 1u,
                                   __ATOMIC_RELAXED, __HIP_MEMORY_SCOPE_AGENT);
        return;
    }

    // ================= update role =================
    int b = bid - NGEMM;
    u32 target = (u32)NGEMM * (u32)((t >> 1) + 1);   // monotonic per parity slot
    if (tid == 0){
        for (;;){
            u32 s = 0;
            #pragma unroll
            for (int i=0;i<16;++i)
                s += __hip_atomic_load(&cnts[(i<<6) + (t & 1)*16],
                                       __ATOMIC_RELAXED, __HIP_MEMORY_SCOPE_AGENT);
            if (s >= target) break;
            __builtin_amdgcn_s_sleep(2);
        }
    }
    __syncthreads();

    const float* Pb = P + (size_t)b*H_;
    int j0 = tid*8;
    float lY[8], lI[8], lPv[8], lN[8], fv[8], ov[8];
    float v0=0,v1=0,v2=0,v3=0;

    float gg[11][8];
    #pragma unroll
    for (int gi=0; gi<11; ++gi){
        const u64* p0 = (const u64*)(Pb + (size_t)gi*BH_ + j0);
        const u64* p1 = (const u64*)(Pb + (size_t)(11+gi)*BH_ + j0);
        #pragma unroll
        for (int q=0;q<4;++q){
            u64 a = aload64(p0+q), d = aload64(p1+q);
            float2 fa, fd;
            __builtin_memcpy(&fa, &a, 8);
            __builtin_memcpy(&fd, &d, 8);
            gg[gi][2*q]   = fa.x + fd.x;
            gg[gi][2*q+1] = fa.y + fd.y;
        }
    }
    #pragma unroll
    for (int q=0;q<8;++q){
        int j = j0 + q;
        fv[q] = sigmf(gg[0][q] + bp.b[0][j]);
        ov[q] = sigmf(gg[1][q] + bp.b[1][j]);
        lY[q]  = tanhfast(gg[2][q] + bp.b[2][j]) * sigmf(gg[6][q] + bp.b[6][j]);
        lI[q]  = tanhfast(gg[3][q] + bp.b[3][j]) * sigmf(gg[7][q] + bp.b[7][j]);
        lPv[q] = tanhfast(gg[4][q] + bp.b[4][j]) * sigmf(gg[8][q] + bp.b[8][j]);
        lN[q]  = tanhfast(gg[5][q] + bp.b[5][j]) * sigmf(gg[9][q] + bp.b[9][j]);
        float gA = gg[10][q];
        v0 += lY[q]*gA; v1 += lI[q]*gA; v2 += lPv[q]*gA; v3 += lN[q]*gA;
    }
    #pragma unroll
    for (int d=32; d>=1; d>>=1){
        v0 += __shfl_down(v0,d); v1 += __shfl_down(v1,d);
        v2 += __shfl_down(v2,d); v3 += __shfl_down(v3,d);
    }
    float* red = (float*)&As[0][0];
    if (lane==0){ red[wid*4+0]=v0; red[wid*4+1]=v1; red[wid*4+2]=v2; red[wid*4+3]=v3; }
    __syncthreads();
    float sY = red[0]+red[4];
    float sI = red[1]+red[5];
    float sP = red[2]+red[6];
    float sN = red[3]+red[7];

    float zp = 0.f;
    #pragma unroll
    for (int q=0;q<8;++q){
        int j = j0 + q;
        zp += __expf(tanhfast(sY + bp.bA[0][j]));
        zp += __expf(tanhfast(sI + bp.bA[1][j]));
        zp += __expf(tanhfast(sP + bp.bA[2][j]));
        zp += __expf(tanhfast(sN + bp.bA[3][j]));
    }
    #pragma unroll
    for (int d=32; d>=1; d>>=1) zp += __shfl_down(zp,d);
    float* zred = red + 8;
    if (lane==0) zred[wid] = zp;
    __syncthreads();
    float Z = zred[0]+zred[1];
    float Zi = 1.0f / Z;
    float a0 = __expf(tanhfast(sY + bp.bA[0][0]))*Zi;
    float a1 = __expf(tanhfast(sY + bp.bA[0][1]))*Zi;
    float a2 = __expf(tanhfast(sY + bp.bA[0][2]))*Zi;
    float a3 = __expf(tanhfast(sY + bp.bA[0][3]))*Zi;

    ushort cb16[8], hb16[8];
    float ho[8];
    #pragma unroll
    for (int q=0;q<8;++q){
        float lT = a0*lY[q] + a1*lI[q] + a2*lPv[q] + a3*lN[q];
        float cn = c[(size_t)b*H_ + j0 + q]*fv[q] + lT;
        c[(size_t)b*H_ + j0 + q] = cn;
        cb16[q] = bf16bits(cn);
        float hn = tanhfast(cn)*ov[q];
        hb16[q] = bf16bits(hn);
        ho[q] = hn;
    }
    *(ulong2*)(cbuf + (size_t)b*H_ + j0) = *(ulong2*)cb16;
    *(ulong2*)(hb   + (size_t)b*H_ + j0) = *(ulong2*)hb16;
    float4* o4 = (float4*)(out + ((size_t)b*T_ + t)*H_ + j0);
    o4[0] = *(float4*)&ho[0];
    o4[1] = *(float4*)&ho[4];
}

extern "C" void kernel_launch(void* const* d_in, const int* in_sizes, int n_in,
                              void* d_out, int out_size, void* d_ws, size_t ws_size,
                              hipStream_t stream)
{
    WPtrs wp; BPtrs bp;
    for (int i=0;i<10;++i){ wp.W[i] = (const float*)d_in[2*i]; bp.b[i] = (const float*)d_in[2*i+1]; }
    wp.wA = (const float*)d_in[20];
    for (int i=0;i<4;++i) bp.bA[i] = (const float*)d_in[21+i];
    const float* xY = (const float*)d_in[25];
    const float* xI = (const float*)d_in[26];
    const float* xP = (const float*)d_in[27];
    const float* xN = (const float*)d_in[28];

    char* w = (char*)d_ws;
    size_t off = 0;
    ushort* Wt  = (ushort*)(w+off); off += (size_t)10*H_*C_*2;        // 31.46 MB
    ushort* wAt = (ushort*)(w+off); off += (size_t)H_*H_*2;           // 2.10 MB
    float*  P   = (float*)(w+off);  off += (size_t)22*BH_*4;          // 23.07 MB
    float*  c   = (float*)(w+off);  off += (size_t)BH_*4;             // 1 MB
    ushort* hb  = (ushort*)(w+off); off += (size_t)BH_*2;             // 0.5 MB
    ushort* cbuf= (ushort*)(w+off); off += (size_t)BH_*2;             // 0.5 MB
    u32*    cnts= (u32*)(w+off);    off += 4096;                      // 4 KB

    // zero c/hb/cbuf (8*BH_ bytes) + counters (contiguous)
    hipMemsetAsync(c, 0, (size_t)BH_*8 + 4096, stream);

    transpose_w<<<dim3(C_/32, H_/32, 11), dim3(32,8), 0, stream>>>(wp, Wt, wAt);

    float* out = (float*)d_out;
    for (int t=0;t<T_;++t){
        fused_step<<<NBLK, 128, 0, stream>>>(Wt, wAt, xY, xI, xP, xN,
                                             hb, cbuf, c, P, bp, out, cnts, t);
    }
}

// Round 12
// 4616.272 us; speedup vs baseline: 1.4203x; 1.4203x over previous
//
#include <hip/hip_runtime.h>
#include <hip/hip_bf16.h>

#define H_ 1024
#define C_ 1536
#define B_ 256
#define T_ 128
#define IN_ 512
#define BH_ (B_*H_)

typedef __hip_bfloat16 bf16;
typedef __attribute__((ext_vector_type(8))) short short8;
typedef __attribute__((ext_vector_type(4))) float f32x4;
typedef unsigned int u32;

struct WPtrs { const float* W[10]; const float* wA; };
struct BPtrs { const float* b[10]; const float* bA[4]; };

__device__ __forceinline__ float sigmf(float x){ return 1.0f/(1.0f + __expf(-x)); }
__device__ __forceinline__ float tanhfast(float x){ return 1.0f - 2.0f/(__expf(2.0f*x) + 1.0f); }

__device__ __forceinline__ ushort bf16bits(float f){
    bf16 b = __float2bfloat16(f);
    return *reinterpret_cast<ushort*>(&b);
}

// async global->LDS, 16B per lane
__device__ __forceinline__ void gload16(const void* g, void* l){
    __builtin_amdgcn_global_load_lds((const __attribute__((address_space(1))) u32*)g,
                                     (__attribute__((address_space(3))) u32*)l, 16, 0, 0);
}

// ---- weight transpose+convert: src fp32 [K][H] -> dst bf16 [H][K]
__global__ void transpose_w(WPtrs wp, ushort* __restrict__ Wt, ushort* __restrict__ wAt)
{
    int g = blockIdx.z;
    int K = (g==10) ? H_ : C_;
    int k0 = blockIdx.x*32, n0 = blockIdx.y*32;
    if (k0 >= K) return;
    const float* src = (g==10) ? wp.wA : wp.W[g];
    __shared__ float tile[32][33];
    int tx = threadIdx.x, ty = threadIdx.y;
    #pragma unroll
    for (int i=0;i<32;i+=8)
        tile[ty+i][tx] = src[(size_t)(k0+ty+i)*H_ + n0 + tx];
    __syncthreads();
    ushort* dst = (g==10) ? wAt : (Wt + (size_t)g*H_*C_);
    #pragma unroll
    for (int i=0;i<32;i+=8)
        dst[(size_t)(n0+ty+i)*K + k0 + tx] = bf16bits(tile[tx][ty+i]);
}

// ---- per-step GEMM, split-K=2, narrow n-tiles for 2x wave concurrency.
// 1408 blocks = 8 XCD x 22 ntile(64) x 4 mtile(64) x 2 ksplit; 128 thr (2 waves),
// wave tile 32(m)x64(n) (acc[2][4]); dbuf LDS 32KB -> 5 blocks/CU resident.
// x-part staged directly from fp32 input via reg path (issue early, write late).
__global__ __launch_bounds__(128, 4) void gemm_step(
    const ushort* __restrict__ Wt, const ushort* __restrict__ wAt,
    const float* __restrict__ xY, const float* __restrict__ xI,
    const float* __restrict__ xPf, const float* __restrict__ xNf,
    const ushort* __restrict__ hb, const ushort* __restrict__ cbuf,
    float* __restrict__ P, int t)
{
    int bid = blockIdx.x;
    int xcd = bid & 7, lid = bid >> 3;     // [0,176)
    int ntile = xcd*22 + (lid >> 3);       // [0,176)
    int rem = lid & 7;
    int mtile = rem >> 1;                  // [0,4)
    int split = rem & 1;                   // [0,2)
    int g = ntile >> 4;                    // 16 n-tiles of 64 per gate
    int n0g = (ntile & 15)*64;
    int m0 = mtile*64;
    bool isA = (g==10);
    const ushort* Bbase = isA ? wAt : (Wt + (size_t)g*H_*C_);
    size_t Bstride = isA ? 1024 : 1536;
    int kStart = isA ? split*512 : split*768;
    int nIter  = isA ? 8 : 12;
    const float* xf = (g==3)?xI:(g==4)?xPf:(g==5)?xNf:xY;
    const ushort* Ah = isA ? cbuf : hb;

    __shared__ ushort As[2][64*64];
    __shared__ ushort Bs[2][64*64];
    int tid = threadIdx.x;
    int wid = tid>>6, lane = tid&63;

    float xr0[8], xr1[8], xr2[8], xr3[8];

    auto stageB = [&](int buf, int k0){
        ushort* lb = Bs[buf];
        #pragma unroll
        for (int it=0; it<4; ++it){            // 64 rows x 8 kc = 512 slots
            int cid = it*128 + tid;
            int row = cid>>3, kc = cid&7;
            int kcs = kc ^ (row&7);
            gload16(Bbase + (size_t)(n0g+row)*Bstride + k0 + kcs*8,
                    lb + (size_t)(it*128 + wid*64)*8);
        }
    };
    auto stageA_h = [&](int buf, int k0){      // k0 tile fully < 1024
        ushort* la = As[buf];
        #pragma unroll
        for (int it=0; it<4; ++it){
            int cid = it*128 + tid;
            int row = cid>>3, kc = cid&7;
            int kcs = kc ^ (row&7);
            gload16(Ah + (size_t)(m0+row)*H_ + k0 + kcs*8,
                    la + (size_t)(it*128 + wid*64)*8);
        }
    };
    auto stageX_issue = [&](int k0){           // k0 >= 1024: x from fp32 input
        #pragma unroll
        for (int it=0; it<4; ++it){
            int cid = it*128 + tid;
            int row = cid>>3, kc = cid&7;
            const float4* s4 = (const float4*)(xf + ((size_t)(m0+row)*T_ + t)*IN_ + (k0 + kc*8 - 1024));
            float4 a = s4[0], b = s4[1];
            float* xr = (it==0)?xr0:(it==1)?xr1:(it==2)?xr2:xr3;
            xr[0]=a.x; xr[1]=a.y; xr[2]=a.z; xr[3]=a.w;
            xr[4]=b.x; xr[5]=b.y; xr[6]=b.z; xr[7]=b.w;
        }
    };
    auto stageX_finish = [&](int buf){
        ushort* la = As[buf];
        #pragma unroll
        for (int it=0; it<4; ++it){
            int cid = it*128 + tid;
            int row = cid>>3, kc = cid&7;
            int kcs = kc ^ (row&7);
            const float* xr = (it==0)?xr0:(it==1)?xr1:(it==2)?xr2:xr3;
            ushort t8[8];
            #pragma unroll
            for (int q=0;q<8;++q) t8[q] = bf16bits(xr[q]);
            *(ulong2*)(la + (size_t)row*64 + kcs*8) = *(ulong2*)t8;
        }
    };

    f32x4 acc[2][4] = {};
    stageA_h(0, kStart);
    stageB(0, kStart);
    __syncthreads();

    int cur = 0;
    for (int i=0; i<nIter; ++i){
        int k0n = kStart + ((i+1)<<6);
        bool more = (i+1 < nIter);
        bool nx_x = false;
        if (more){
            nx_x = (!isA) && (k0n >= 1024);
            if (nx_x) stageX_issue(k0n);
            else      stageA_h(cur^1, k0n);
            stageB(cur^1, k0n);
        }
        ushort* la = As[cur];
        ushort* lb = Bs[cur];
        #pragma unroll
        for (int kk=0; kk<2; ++kk){
            short8 af[2], bfr[4];
            #pragma unroll
            for (int mr=0;mr<2;++mr){
                int r = wid*32 + mr*16 + (lane&15);
                int j = (kk*4 + (lane>>4)) ^ (r&7);
                af[mr] = *(const short8*)(la + r*64 + j*8);
            }
            #pragma unroll
            for (int nr=0;nr<4;++nr){
                int r = nr*16 + (lane&15);
                int j = (kk*4 + (lane>>4)) ^ (r&7);
                bfr[nr] = *(const short8*)(lb + r*64 + j*8);
            }
            #pragma unroll
            for (int mr=0;mr<2;++mr)
                #pragma unroll
                for (int nr=0;nr<4;++nr)
                    acc[mr][nr] = __builtin_amdgcn_mfma_f32_16x16x32_bf16(af[mr], bfr[nr], acc[mr][nr], 0,0,0);
        }
        if (more && nx_x) stageX_finish(cur^1);
        __syncthreads();
        cur ^= 1;
    }

    float* Pg = P + ((size_t)split*11 + g)*BH_;
    #pragma unroll
    for (int mr=0;mr<2;++mr){
        #pragma unroll
        for (int nr=0;nr<4;++nr){
            int col = n0g + nr*16 + (lane&15);
            #pragma unroll
            for (int r=0;r<4;++r){
                int rowg = m0 + wid*32 + mr*16 + (lane>>4)*4 + r;
                Pg[(size_t)rowg*H_ + col] = acc[mr][nr][r];
            }
        }
    }
}

// ---- per-row: sum split-K partials -> gates -> scores -> Z -> softmax -> c,h
__global__ __launch_bounds__(1024) void step_update(
    const float* __restrict__ P, BPtrs bp,
    float* __restrict__ c, ushort* __restrict__ hb, ushort* __restrict__ cbuf,
    float* __restrict__ out, int t)
{
    int b = blockIdx.x;
    int j = threadIdx.x;
    int wid = j>>6, lane = j&63;
    const float* Pb = P + (size_t)b*H_;

    auto gp = [&](int g){
        return Pb[(size_t)g*BH_ + j] + Pb[(size_t)(11+g)*BH_ + j];
    };

    float fv = sigmf(gp(0) + bp.b[0][j]);
    float ov = sigmf(gp(1) + bp.b[1][j]);
    float lY = tanhfast(gp(2) + bp.b[2][j]) * sigmf(gp(6) + bp.b[6][j]);
    float lI = tanhfast(gp(3) + bp.b[3][j]) * sigmf(gp(7) + bp.b[7][j]);
    float lP = tanhfast(gp(4) + bp.b[4][j]) * sigmf(gp(8) + bp.b[8][j]);
    float lN = tanhfast(gp(5) + bp.b[5][j]) * sigmf(gp(9) + bp.b[9][j]);
    float cw = gp(10);

    float v0=lY*cw, v1=lI*cw, v2=lP*cw, v3=lN*cw;
    #pragma unroll
    for (int d=32; d>=1; d>>=1){
        v0 += __shfl_down(v0,d); v1 += __shfl_down(v1,d);
        v2 += __shfl_down(v2,d); v3 += __shfl_down(v3,d);
    }
    __shared__ float red[16][4];
    if (lane==0){ red[wid][0]=v0; red[wid][1]=v1; red[wid][2]=v2; red[wid][3]=v3; }
    __syncthreads();
    float sY=0, sI=0, sP=0, sN=0;
    #pragma unroll
    for (int w=0; w<16; ++w){
        sY += red[w][0]; sI += red[w][1]; sP += red[w][2]; sN += red[w][3];
    }

    float zp = __expf(tanhfast(sY + bp.bA[0][j]))
             + __expf(tanhfast(sI + bp.bA[1][j]))
             + __expf(tanhfast(sP + bp.bA[2][j]))
             + __expf(tanhfast(sN + bp.bA[3][j]));
    #pragma unroll
    for (int d=32; d>=1; d>>=1) zp += __shfl_down(zp,d);
    __shared__ float zred[16];
    if (lane==0) zred[wid] = zp;
    __syncthreads();
    float Z = 0;
    #pragma unroll
    for (int w=0; w<16; ++w) Z += zred[w];
    float Zi = 1.0f / Z;
    float a0 = __expf(tanhfast(sY + bp.bA[0][0]))*Zi;
    float a1 = __expf(tanhfast(sY + bp.bA[0][1]))*Zi;
    float a2 = __expf(tanhfast(sY + bp.bA[0][2]))*Zi;
    float a3 = __expf(tanhfast(sY + bp.bA[0][3]))*Zi;

    float lT = a0*lY + a1*lI + a2*lP + a3*lN;
    float cn = c[(size_t)b*H_ + j]*fv + lT;
    c[(size_t)b*H_ + j] = cn;
    cbuf[(size_t)b*H_ + j] = bf16bits(cn);
    float hn = tanhfast(cn)*ov;
    hb[(size_t)b*H_ + j] = bf16bits(hn);
    out[((size_t)b*T_ + t)*H_ + j] = hn;
}

extern "C" void kernel_launch(void* const* d_in, const int* in_sizes, int n_in,
                              void* d_out, int out_size, void* d_ws, size_t ws_size,
                              hipStream_t stream)
{
    WPtrs wp; BPtrs bp;
    for (int i=0;i<10;++i){ wp.W[i] = (const float*)d_in[2*i]; bp.b[i] = (const float*)d_in[2*i+1]; }
    wp.wA = (const float*)d_in[20];
    for (int i=0;i<4;++i) bp.bA[i] = (const float*)d_in[21+i];
    const float* xY = (const float*)d_in[25];
    const float* xI = (const float*)d_in[26];
    const float* xP = (const float*)d_in[27];
    const float* xN = (const float*)d_in[28];

    char* w = (char*)d_ws;
    size_t off = 0;
    ushort* Wt  = (ushort*)(w+off); off += (size_t)10*H_*C_*2;        // 31.46 MB
    ushort* wAt = (ushort*)(w+off); off += (size_t)H_*H_*2;           // 2.10 MB
    float*  P   = (float*)(w+off);  off += (size_t)22*BH_*4;          // 23.07 MB
    float*  c   = (float*)(w+off);  off += (size_t)BH_*4;             // 1 MB
    ushort* hb  = (ushort*)(w+off); off += (size_t)BH_*2;             // 0.5 MB
    ushort* cbuf= (ushort*)(w+off); off += (size_t)BH_*2;             // 0.5 MB

    // zero c (fp32) + hb + cbuf (contiguous 8*BH_ bytes)
    hipMemsetAsync(c, 0, (size_t)BH_*8, stream);

    transpose_w<<<dim3(C_/32, H_/32, 11), dim3(32,8), 0, stream>>>(wp, Wt, wAt);

    float* out = (float*)d_out;
    for (int t=0;t<T_;++t){
        gemm_step<<<1408, 128, 0, stream>>>(Wt, wAt, xY, xI, xP, xN, hb, cbuf, P, t);
        step_update<<<B_, 1024, 0, stream>>>(P, bp, c, hb, cbuf, out, t);
    }
}